// Round 1
// baseline (3169.639 us; speedup 1.0000x reference)
//
#include <hip/hip_runtime.h>
#include <math.h>

#define EPSV   1e-5f
#define SLOPE  0.2f

// dims (fixed by the problem)
#define B_   2
#define N_   2048
#define M_   64
#define C_   128    // stage1 channels
#define C2_  256    // stage2/3 channels
#define H_   128    // fc1 out
#define O_   64     // fc2 out

// workspace layout (float offsets). Total ≈ 10.6 MB.
#define WS_H1     0            // [B_*N_*C_] = 524288   (reused as X4 later)
#define WS_HC     524288       // [B_*M_*C_] = 16384
#define WS_SC1    540672
#define WS_SH1    540800
#define WS_SUM2   540928
#define WS_SSQ2   541184
#define WS_SC2    541440
#define WS_SH2    541696
#define WS_SUM3   541952
#define WS_SSQ3   542208
#define WS_SC3    542464
#define WS_SH3    542720
#define WS_SUM4   542976
#define WS_SSQ4   543104
#define WS_SC4    543232
#define WS_SH4    543360
#define WS_SUM5   543488
#define WS_SSQ5   543552
#define WS_SC5    543616
#define WS_SH5    543680
#define WS_XMAX   543744       // [B_*N_*C2_] = 1048576
#define WS_XMIN   1592320      // [B_*N_*C2_] = 1048576  (reused as X5 later)
#define WS_X4     WS_H1
#define WS_X5     WS_XMIN
#define WS_ZERO_BEG WS_SUM2
#define WS_ZERO_CNT (WS_SH5 + O_ - WS_SUM2)   // 2816 floats: all stat buffers

// ---------------------------------------------------------------- projections
// out[row][o] = sum_c x[row][c] * W1[o][col_off + c]   (W1 row stride 2*C_)
__global__ __launch_bounds__(128) void k_proj(const float* __restrict__ x,
                                              const float* __restrict__ W1,
                                              float* __restrict__ out, int col_off) {
  int row = blockIdx.x, t = threadIdx.x;
  __shared__ float xs[C_];
  xs[t] = x[row * C_ + t];
  __syncthreads();
  const float* w = W1 + t * (2 * C_) + col_off;
  float acc = 0.f;
#pragma unroll
  for (int c = 0; c < C_; c += 4) {
    float4 wv = *(const float4*)(w + c);
    float4 xv = *(const float4*)(xs + c);
    acc = fmaf(wv.x, xv.x, fmaf(wv.y, xv.y, fmaf(wv.z, xv.z, fmaf(wv.w, xv.w, acc))));
  }
  out[row * C_ + t] = acc;
}

// ---------------------------------------------------------------- stats1 (analytic)
__device__ inline float blk_reduce256(float v, float* red) {
  int t = threadIdx.x;
  __syncthreads();
  red[t] = v;
  __syncthreads();
  for (int s = 128; s > 0; s >>= 1) {
    if (t < s) red[t] += red[t + s];
    __syncthreads();
  }
  return red[0];
}

// X1[b,n,m,c] = h1[b,n,c] + hc[b,m,c]; per-channel mean/var over (b,n,m), analytic.
__global__ __launch_bounds__(256) void k_stats1(const float* __restrict__ h1,
                                                const float* __restrict__ hc,
                                                const float* __restrict__ g,
                                                const float* __restrict__ bt,
                                                float* __restrict__ scale,
                                                float* __restrict__ shift) {
  __shared__ float red[256];
  int c = blockIdx.x, t = threadIdx.x;
  float sA[B_], sA2[B_], sC[B_], sC2[B_];
  for (int b = 0; b < B_; ++b) {
    float s = 0.f, s2 = 0.f;
    for (int n = t; n < N_; n += 256) {
      float v = h1[((b << 11) + n) * C_ + c];
      s += v; s2 = fmaf(v, v, s2);
    }
    sA[b]  = blk_reduce256(s, red);
    sA2[b] = blk_reduce256(s2, red);
    s = 0.f; s2 = 0.f;
    if (t < M_) {
      float v = hc[((b << 6) + t) * C_ + c];
      s = v; s2 = v * v;
    }
    sC[b]  = blk_reduce256(s, red);
    sC2[b] = blk_reduce256(s2, red);
  }
  if (t == 0) {
    const float cnt = (float)B_ * N_ * M_;
    float sAt = sA[0] + sA[1], sCt = sC[0] + sC[1];
    float mean = ((float)M_ * sAt + (float)N_ * sCt) / cnt;
    float ex2 = ((float)M_ * (sA2[0] + sA2[1]) + (float)N_ * (sC2[0] + sC2[1])
                 + 2.f * (sA[0] * sC[0] + sA[1] * sC[1])) / cnt;
    float var = ex2 - mean * mean;
    float sc = g[c] * rsqrtf(var + EPSV);
    scale[c] = sc;
    shift[c] = bt[c] - mean * sc;
  }
}

// ---------------------------------------------------------------- shared S1 build
// S1[m][c] = lrelu(scale1[c]*(h1[row][c]+hc[b][m][c]) + shift1[c]), block = 256 thr
__device__ inline void build_S1(float (*S1)[C_], const float* __restrict__ h1,
                                const float* __restrict__ hc,
                                const float* __restrict__ sc1g,
                                const float* __restrict__ sh1g, int row) {
  int t = threadIdx.x;
  __shared__ float h1row[C_], sc1[C_], sh1[C_];
  if (t < C_) {
    h1row[t] = h1[row * C_ + t];
    sc1[t] = sc1g[t];
    sh1[t] = sh1g[t];
  }
  __syncthreads();
  int b = row >> 11;  // row = b*N_+n
  const float* hcb = hc + (b * M_) * C_;
  for (int idx = t; idx < M_ * (C_ / 4); idx += 256) {
    int m = idx >> 5, c4 = (idx & 31) << 2;
    float4 hv = *(const float4*)(hcb + m * C_ + c4);
    float4 r; float x;
    x = fmaf(sc1[c4+0], h1row[c4+0] + hv.x, sh1[c4+0]); r.x = x > 0.f ? x : SLOPE * x;
    x = fmaf(sc1[c4+1], h1row[c4+1] + hv.y, sh1[c4+1]); r.y = x > 0.f ? x : SLOPE * x;
    x = fmaf(sc1[c4+2], h1row[c4+2] + hv.z, sh1[c4+2]); r.z = x > 0.f ? x : SLOPE * x;
    x = fmaf(sc1[c4+3], h1row[c4+3] + hv.w, sh1[c4+3]); r.w = x > 0.f ? x : SLOPE * x;
    *(float4*)(&S1[m][c4]) = r;
  }
  __syncthreads();
}

// ---------------------------------------------------------------- pass B: stats of X2
__global__ __launch_bounds__(256) void k_stats2(const float* __restrict__ h1,
                                                const float* __restrict__ hc,
                                                const float* __restrict__ sc1,
                                                const float* __restrict__ sh1,
                                                const float* __restrict__ W2,
                                                float* __restrict__ sum2,
                                                float* __restrict__ ssq2) {
  __shared__ float S1[M_][C_];
  int row = blockIdx.x;
  build_S1(S1, h1, hc, sc1, sh1, row);
  int o = threadIdx.x;                    // 256 output channels
  const float* w = W2 + o * C_;
  float acc[M_];
#pragma unroll
  for (int m = 0; m < M_; ++m) acc[m] = 0.f;
  for (int c0 = 0; c0 < C_; c0 += 4) {
    float4 wv = *(const float4*)(w + c0);
#pragma unroll
    for (int m = 0; m < M_; ++m) {
      float4 sv = *(const float4*)(&S1[m][c0]);   // broadcast across lanes
      acc[m] = fmaf(wv.x, sv.x, fmaf(wv.y, sv.y, fmaf(wv.z, sv.z, fmaf(wv.w, sv.w, acc[m]))));
    }
  }
  float s = 0.f, s2 = 0.f;
#pragma unroll
  for (int m = 0; m < M_; ++m) { s += acc[m]; s2 = fmaf(acc[m], acc[m], s2); }
  atomicAdd(&sum2[o], s);
  atomicAdd(&ssq2[o], s2);
}

// ---------------------------------------------------------------- finalize BN params
__global__ void k_finalize(const float* __restrict__ sum, const float* __restrict__ ssq,
                           const float* __restrict__ g, const float* __restrict__ bt,
                           float* __restrict__ scale, float* __restrict__ shift,
                           int nch, float inv_cnt) {
  int o = threadIdx.x + blockIdx.x * blockDim.x;
  if (o < nch) {
    float mean = sum[o] * inv_cnt;
    float var = ssq[o] * inv_cnt - mean * mean;
    float sc = g[o] * rsqrtf(var + EPSV);
    scale[o] = sc;
    shift[o] = bt[o] - mean * sc;
  }
}

// ---------------------------------------------------------------- pass C: S2, X3 stats + max/min pool
__global__ __launch_bounds__(256) void k_stage3(const float* __restrict__ h1,
                                                const float* __restrict__ hc,
                                                const float* __restrict__ sc1,
                                                const float* __restrict__ sh1,
                                                const float* __restrict__ W2,
                                                const float* __restrict__ sc2,
                                                const float* __restrict__ sh2,
                                                const float* __restrict__ W3,
                                                float* __restrict__ sum3,
                                                float* __restrict__ ssq3,
                                                float* __restrict__ Xmax,
                                                float* __restrict__ Xmin) {
  __shared__ float S1[M_][C_];    // 32 KB
  __shared__ float S2[M_][C2_];   // 64 KB
  int row = blockIdx.x;
  build_S1(S1, h1, hc, sc1, sh1, row);
  int o = threadIdx.x;
  {
    const float* w = W2 + o * C_;
    float acc[M_];
#pragma unroll
    for (int m = 0; m < M_; ++m) acc[m] = 0.f;
    for (int c0 = 0; c0 < C_; c0 += 4) {
      float4 wv = *(const float4*)(w + c0);
#pragma unroll
      for (int m = 0; m < M_; ++m) {
        float4 sv = *(const float4*)(&S1[m][c0]);
        acc[m] = fmaf(wv.x, sv.x, fmaf(wv.y, sv.y, fmaf(wv.z, sv.z, fmaf(wv.w, sv.w, acc[m]))));
      }
    }
    float sc = sc2[o], sh = sh2[o];
#pragma unroll
    for (int m = 0; m < M_; ++m) {
      float x2 = fmaf(sc, acc[m], sh);
      S2[m][o] = x2 > 0.f ? x2 : SLOPE * x2;   // lanes write consecutive o: no conflict
    }
  }
  __syncthreads();
  {
    const float* w = W3 + o * C2_;
    float acc[M_];
#pragma unroll
    for (int m = 0; m < M_; ++m) acc[m] = 0.f;
    for (int c0 = 0; c0 < C2_; c0 += 4) {
      float4 wv = *(const float4*)(w + c0);
#pragma unroll
      for (int m = 0; m < M_; ++m) {
        float4 sv = *(const float4*)(&S2[m][c0]);
        acc[m] = fmaf(wv.x, sv.x, fmaf(wv.y, sv.y, fmaf(wv.z, sv.z, fmaf(wv.w, sv.w, acc[m]))));
      }
    }
    float s = 0.f, s2 = 0.f, mx = -1e30f, mn = 1e30f;
#pragma unroll
    for (int m = 0; m < M_; ++m) {
      s += acc[m];
      s2 = fmaf(acc[m], acc[m], s2);
      mx = fmaxf(mx, acc[m]);
      mn = fminf(mn, acc[m]);
    }
    atomicAdd(&sum3[o], s);
    atomicAdd(&ssq3[o], s2);
    Xmax[row * C2_ + o] = mx;
    Xmin[row * C2_ + o] = mn;
  }
}

// ---------------------------------------------------------------- pool + fc1 (+stats4)
__global__ __launch_bounds__(128) void k_fc1(const float* __restrict__ Xmax,
                                             const float* __restrict__ Xmin,
                                             const float* __restrict__ sc3,
                                             const float* __restrict__ sh3,
                                             const float* __restrict__ w1,
                                             const float* __restrict__ b1v,
                                             float* __restrict__ X4,
                                             float* __restrict__ sum4,
                                             float* __restrict__ ssq4) {
  __shared__ float pooled[C2_];
  int row = blockIdx.x, t = threadIdx.x;
  for (int o = t; o < C2_; o += 128) {
    float sc = sc3[o];
    // lrelu∘affine is monotone; direction flips with sign(scale3)
    float v = sc >= 0.f ? Xmax[row * C2_ + o] : Xmin[row * C2_ + o];
    float x = fmaf(sc, v, sh3[o]);
    pooled[o] = x > 0.f ? x : SLOPE * x;
  }
  __syncthreads();
  const float* w = w1 + t * C2_;
  float acc = b1v[t];
#pragma unroll
  for (int c = 0; c < C2_; c += 4) {
    float4 wv = *(const float4*)(w + c);
    float4 pv = *(const float4*)(&pooled[c]);
    acc = fmaf(wv.x, pv.x, fmaf(wv.y, pv.y, fmaf(wv.z, pv.z, fmaf(wv.w, pv.w, acc))));
  }
  X4[row * H_ + t] = acc;
  atomicAdd(&sum4[t], acc);
  atomicAdd(&ssq4[t], acc * acc);
}

// ---------------------------------------------------------------- bn4+relu + fc2 (+stats5)
__global__ __launch_bounds__(64) void k_fc2(const float* __restrict__ X4,
                                            const float* __restrict__ sc4,
                                            const float* __restrict__ sh4,
                                            const float* __restrict__ w2,
                                            const float* __restrict__ b2v,
                                            float* __restrict__ X5,
                                            float* __restrict__ sum5,
                                            float* __restrict__ ssq5) {
  __shared__ float y[H_];
  int row = blockIdx.x, t = threadIdx.x;
  for (int j = t; j < H_; j += 64) {
    float x = fmaf(sc4[j], X4[row * H_ + j], sh4[j]);
    y[j] = x > 0.f ? x : 0.f;
  }
  __syncthreads();
  const float* w = w2 + t * H_;
  float acc = b2v[t];
#pragma unroll
  for (int c = 0; c < H_; c += 4) {
    float4 wv = *(const float4*)(w + c);
    float4 yv = *(const float4*)(&y[c]);
    acc = fmaf(wv.x, yv.x, fmaf(wv.y, yv.y, fmaf(wv.z, yv.z, fmaf(wv.w, yv.w, acc))));
  }
  X5[row * O_ + t] = acc;
  atomicAdd(&sum5[t], acc);
  atomicAdd(&ssq5[t], acc * acc);
}

// ---------------------------------------------------------------- bn5 + relu -> out
__global__ __launch_bounds__(256) void k_out(const float* __restrict__ X5,
                                             const float* __restrict__ sc5,
                                             const float* __restrict__ sh5,
                                             float* __restrict__ out) {
  int i = blockIdx.x * 256 + threadIdx.x;   // grid sized exactly
  float x = fmaf(sc5[i & (O_ - 1)], X5[i], sh5[i & (O_ - 1)]);
  out[i] = x > 0.f ? x : 0.f;
}

// ---------------------------------------------------------------- launch
extern "C" void kernel_launch(void* const* d_in, const int* in_sizes, int n_in,
                              void* d_out, int out_size, void* d_ws, size_t ws_size,
                              hipStream_t stream) {
  const float* pf   = (const float*)d_in[0];
  const float* cf   = (const float*)d_in[1];
  const float* W1   = (const float*)d_in[2];
  const float* g1   = (const float*)d_in[3];
  const float* b1   = (const float*)d_in[4];
  const float* W2   = (const float*)d_in[5];
  const float* g2   = (const float*)d_in[6];
  const float* b2   = (const float*)d_in[7];
  const float* W3   = (const float*)d_in[8];
  const float* g3   = (const float*)d_in[9];
  const float* b3   = (const float*)d_in[10];
  const float* fc1w = (const float*)d_in[11];
  const float* fc1b = (const float*)d_in[12];
  const float* g4   = (const float*)d_in[13];
  const float* b4   = (const float*)d_in[14];
  const float* fc2w = (const float*)d_in[15];
  const float* fc2b = (const float*)d_in[16];
  const float* g5   = (const float*)d_in[17];
  const float* b5   = (const float*)d_in[18];
  float* ws  = (float*)d_ws;
  float* out = (float*)d_out;

  // zero all stat accumulators (graph-capturable)
  hipMemsetAsync(ws + WS_ZERO_BEG, 0, WS_ZERO_CNT * sizeof(float), stream);

  k_proj<<<B_ * N_, 128, 0, stream>>>(pf, W1, ws + WS_H1, 0);
  k_proj<<<B_ * M_, 128, 0, stream>>>(cf, W1, ws + WS_HC, C_);
  k_stats1<<<C_, 256, 0, stream>>>(ws + WS_H1, ws + WS_HC, g1, b1, ws + WS_SC1, ws + WS_SH1);
  k_stats2<<<B_ * N_, 256, 0, stream>>>(ws + WS_H1, ws + WS_HC, ws + WS_SC1, ws + WS_SH1,
                                        W2, ws + WS_SUM2, ws + WS_SSQ2);
  k_finalize<<<1, C2_, 0, stream>>>(ws + WS_SUM2, ws + WS_SSQ2, g2, b2,
                                    ws + WS_SC2, ws + WS_SH2, C2_, 1.f / (B_ * N_ * M_));
  k_stage3<<<B_ * N_, 256, 0, stream>>>(ws + WS_H1, ws + WS_HC, ws + WS_SC1, ws + WS_SH1,
                                        W2, ws + WS_SC2, ws + WS_SH2, W3,
                                        ws + WS_SUM3, ws + WS_SSQ3,
                                        ws + WS_XMAX, ws + WS_XMIN);
  k_finalize<<<1, C2_, 0, stream>>>(ws + WS_SUM3, ws + WS_SSQ3, g3, b3,
                                    ws + WS_SC3, ws + WS_SH3, C2_, 1.f / (B_ * N_ * M_));
  k_fc1<<<B_ * N_, 128, 0, stream>>>(ws + WS_XMAX, ws + WS_XMIN, ws + WS_SC3, ws + WS_SH3,
                                     fc1w, fc1b, ws + WS_X4, ws + WS_SUM4, ws + WS_SSQ4);
  k_finalize<<<1, H_, 0, stream>>>(ws + WS_SUM4, ws + WS_SSQ4, g4, b4,
                                   ws + WS_SC4, ws + WS_SH4, H_, 1.f / (B_ * N_));
  k_fc2<<<B_ * N_, 64, 0, stream>>>(ws + WS_X4, ws + WS_SC4, ws + WS_SH4,
                                    fc2w, fc2b, ws + WS_X5, ws + WS_SUM5, ws + WS_SSQ5);
  k_finalize<<<1, O_, 0, stream>>>(ws + WS_SUM5, ws + WS_SSQ5, g5, b5,
                                   ws + WS_SC5, ws + WS_SH5, O_, 1.f / (B_ * N_));
  k_out<<<(B_ * N_ * O_) / 256, 256, 0, stream>>>(ws + WS_X5, ws + WS_SC5, ws + WS_SH5, out);
}

// Round 2
// 529.878 us; speedup vs baseline: 5.9818x; 5.9818x over previous
//
#include <hip/hip_runtime.h>
#include <math.h>

#define EPSV   1e-5f
#define SLOPE  0.2f

// dims (fixed by the problem)
#define B_   2
#define N_   2048
#define M_   64
#define C_   128    // stage1 channels
#define C2_  256    // stage2/3 channels
#define H_   128    // fc1 out
#define O_   64     // fc2 out

typedef short  s16x8 __attribute__((ext_vector_type(8)));   // 8 bf16 (4 VGPRs)
typedef ushort u16x8 __attribute__((ext_vector_type(8)));
typedef float  f32x4 __attribute__((ext_vector_type(4)));

// workspace layout (float offsets)
#define WS_H1     0            // [B_*N_*C_] = 524288   (reused as X4 later)
#define WS_HC     524288       // [B_*M_*C_] = 16384
#define WS_SC1    540672
#define WS_SH1    540800
#define WS_SUM2   540928
#define WS_SSQ2   541184
#define WS_SC2    541440
#define WS_SH2    541696
#define WS_SUM3   541952
#define WS_SSQ3   542208
#define WS_SC3    542464
#define WS_SH3    542720
#define WS_SUM4   542976
#define WS_SSQ4   543104
#define WS_SC4    543232
#define WS_SH4    543360
#define WS_SUM5   543488
#define WS_SSQ5   543552
#define WS_SC5    543616
#define WS_SH5    543680
#define WS_XMAX   543744       // [B_*N_*C2_] = 1048576
#define WS_XMIN   1592320      // [B_*N_*C2_] = 1048576  (reused as X5 later)
#define WS_W2BF   2640896      // 256*128 bf16 = 16384 floats
#define WS_W3BF   2657280      // 256*256 bf16 = 32768 floats
#define WS_X4     WS_H1
#define WS_X5     WS_XMIN
#define WS_ZERO_BEG WS_SUM2
#define WS_ZERO_CNT (WS_SH5 + O_ - WS_SUM2)

__device__ inline ushort f2b(float x) {          // f32 -> bf16 RNE (finite inputs)
  unsigned u = __builtin_bit_cast(unsigned, x);
  u += 0x7fffu + ((u >> 16) & 1u);
  return (ushort)(u >> 16);
}

// ---------------------------------------------------------------- W -> bf16
__global__ __launch_bounds__(256) void k_cvtW(const float* __restrict__ W2,
                                              const float* __restrict__ W3,
                                              ushort* __restrict__ w2b,
                                              ushort* __restrict__ w3b) {
  int i = blockIdx.x * 256 + threadIdx.x;      // grid covers 65536
  if (i < C2_ * C_) w2b[i] = f2b(W2[i]);
  w3b[i] = f2b(W3[i]);
}

// ---------------------------------------------------------------- projections (fp32)
__global__ __launch_bounds__(128) void k_proj(const float* __restrict__ x,
                                              const float* __restrict__ W1,
                                              float* __restrict__ out, int col_off) {
  int row = blockIdx.x, t = threadIdx.x;
  __shared__ float xs[C_];
  xs[t] = x[row * C_ + t];
  __syncthreads();
  const float* w = W1 + t * (2 * C_) + col_off;
  float acc = 0.f;
#pragma unroll
  for (int c = 0; c < C_; c += 4) {
    float4 wv = *(const float4*)(w + c);
    float4 xv = *(const float4*)(xs + c);
    acc = fmaf(wv.x, xv.x, fmaf(wv.y, xv.y, fmaf(wv.z, xv.z, fmaf(wv.w, xv.w, acc))));
  }
  out[row * C_ + t] = acc;
}

// ---------------------------------------------------------------- stats1 (analytic)
__device__ inline float blk_reduce256(float v, float* red) {
  int t = threadIdx.x;
  __syncthreads();
  red[t] = v;
  __syncthreads();
  for (int s = 128; s > 0; s >>= 1) {
    if (t < s) red[t] += red[t + s];
    __syncthreads();
  }
  return red[0];
}

__global__ __launch_bounds__(256) void k_stats1(const float* __restrict__ h1,
                                                const float* __restrict__ hc,
                                                const float* __restrict__ g,
                                                const float* __restrict__ bt,
                                                float* __restrict__ scale,
                                                float* __restrict__ shift) {
  __shared__ float red[256];
  int c = blockIdx.x, t = threadIdx.x;
  float sA[B_], sA2[B_], sC[B_], sC2[B_];
  for (int b = 0; b < B_; ++b) {
    float s = 0.f, s2 = 0.f;
    for (int n = t; n < N_; n += 256) {
      float v = h1[((b << 11) + n) * C_ + c];
      s += v; s2 = fmaf(v, v, s2);
    }
    sA[b]  = blk_reduce256(s, red);
    sA2[b] = blk_reduce256(s2, red);
    s = 0.f; s2 = 0.f;
    if (t < M_) {
      float v = hc[((b << 6) + t) * C_ + c];
      s = v; s2 = v * v;
    }
    sC[b]  = blk_reduce256(s, red);
    sC2[b] = blk_reduce256(s2, red);
  }
  if (t == 0) {
    const float cnt = (float)B_ * N_ * M_;
    float sAt = sA[0] + sA[1], sCt = sC[0] + sC[1];
    float mean = ((float)M_ * sAt + (float)N_ * sCt) / cnt;
    float ex2 = ((float)M_ * (sA2[0] + sA2[1]) + (float)N_ * (sC2[0] + sC2[1])
                 + 2.f * (sA[0] * sC[0] + sA[1] * sC[1])) / cnt;
    float var = ex2 - mean * mean;
    float sc = g[c] * rsqrtf(var + EPSV);
    scale[c] = sc;
    shift[c] = bt[c] - mean * sc;
  }
}

// ---------------------------------------------------------------- S1 build (bf16, swizzled)
// S1 element (m,c) lives at ushort index m*128 + (((c>>3) ^ (m&7))<<3) + (c&7)
__device__ inline void build_S1(ushort* S1, const float* __restrict__ h1,
                                const float* __restrict__ hc,
                                const float* __restrict__ sc1g,
                                const float* __restrict__ sh1g, int row,
                                float* h1row, float* sc1, float* sh1) {
  int t = threadIdx.x;
  if (t < C_) {
    h1row[t] = h1[row * C_ + t];
    sc1[t] = sc1g[t];
    sh1[t] = sh1g[t];
  }
  __syncthreads();
  const float* hcb = hc + (row >> 11) * M_ * C_;
  for (int s = t; s < M_ * 16; s += 256) {     // one 8-elem slot per iter
    int m = s >> 4, j = s & 15, c0 = j << 3;
    const float* src = hcb + m * C_ + c0;
    float4 v0 = *(const float4*)(src);
    float4 v1 = *(const float4*)(src + 4);
    u16x8 r;
    float x;
    x = fmaf(sc1[c0+0], h1row[c0+0] + v0.x, sh1[c0+0]); r[0] = f2b(x > 0.f ? x : SLOPE * x);
    x = fmaf(sc1[c0+1], h1row[c0+1] + v0.y, sh1[c0+1]); r[1] = f2b(x > 0.f ? x : SLOPE * x);
    x = fmaf(sc1[c0+2], h1row[c0+2] + v0.z, sh1[c0+2]); r[2] = f2b(x > 0.f ? x : SLOPE * x);
    x = fmaf(sc1[c0+3], h1row[c0+3] + v0.w, sh1[c0+3]); r[3] = f2b(x > 0.f ? x : SLOPE * x);
    x = fmaf(sc1[c0+4], h1row[c0+4] + v1.x, sh1[c0+4]); r[4] = f2b(x > 0.f ? x : SLOPE * x);
    x = fmaf(sc1[c0+5], h1row[c0+5] + v1.y, sh1[c0+5]); r[5] = f2b(x > 0.f ? x : SLOPE * x);
    x = fmaf(sc1[c0+6], h1row[c0+6] + v1.z, sh1[c0+6]); r[6] = f2b(x > 0.f ? x : SLOPE * x);
    x = fmaf(sc1[c0+7], h1row[c0+7] + v1.w, sh1[c0+7]); r[7] = f2b(x > 0.f ? x : SLOPE * x);
    *(u16x8*)(S1 + m * C_ + ((j ^ (m & 7)) << 3)) = r;
  }
  __syncthreads();
}

// ---------------------------------------------------------------- pass B: stats of X2 (MFMA)
__global__ __launch_bounds__(256) void k_stats2(const float* __restrict__ h1,
                                                const float* __restrict__ hc,
                                                const float* __restrict__ sc1g,
                                                const float* __restrict__ sh1g,
                                                const ushort* __restrict__ W2b,
                                                float* __restrict__ sum2,
                                                float* __restrict__ ssq2) {
  __shared__ __align__(16) ushort S1[M_ * C_];
  __shared__ float h1row[C_], sc1[C_], sh1[C_];
  int row = blockIdx.x;
  build_S1(S1, h1, hc, sc1g, sh1g, row, h1row, sc1, sh1);
  int t = threadIdx.x, w = t >> 6, lane = t & 63, lr = lane & 15, lg = lane >> 4;

  s16x8 b2[4][4];
  const ushort* w2base = W2b + (w * 64 + lr) * C_ + lg * 8;
#pragma unroll
  for (int ot = 0; ot < 4; ++ot)
#pragma unroll
    for (int ks = 0; ks < 4; ++ks)
      b2[ot][ks] = *(const s16x8*)(w2base + ot * 16 * C_ + ks * 32);

  float sm[4] = {0.f, 0.f, 0.f, 0.f}, sq[4] = {0.f, 0.f, 0.f, 0.f};
#pragma unroll
  for (int mt = 0; mt < 4; ++mt) {
    int rowm = mt * 16 + lr, rx = rowm & 7;
    const ushort* s1r = S1 + rowm * C_;
    s16x8 a[4];
#pragma unroll
    for (int ks = 0; ks < 4; ++ks)
      a[ks] = *(const s16x8*)(s1r + (((ks * 4 + lg) ^ rx) << 3));
#pragma unroll
    for (int ot = 0; ot < 4; ++ot) {
      f32x4 acc = {0.f, 0.f, 0.f, 0.f};
#pragma unroll
      for (int ks = 0; ks < 4; ++ks)
        acc = __builtin_amdgcn_mfma_f32_16x16x32_bf16(a[ks], b2[ot][ks], acc, 0, 0, 0);
#pragma unroll
      for (int r = 0; r < 4; ++r) {
        float v = acc[r];
        sm[ot] += v;
        sq[ot] = fmaf(v, v, sq[ot]);
      }
    }
  }
#pragma unroll
  for (int ot = 0; ot < 4; ++ot) {
    sm[ot] += __shfl_xor(sm[ot], 16); sm[ot] += __shfl_xor(sm[ot], 32);
    sq[ot] += __shfl_xor(sq[ot], 16); sq[ot] += __shfl_xor(sq[ot], 32);
  }
  if (lg == 0) {
#pragma unroll
    for (int ot = 0; ot < 4; ++ot) {
      int o = w * 64 + ot * 16 + lr;
      atomicAdd(&sum2[o], sm[ot]);
      atomicAdd(&ssq2[o], sq[ot]);
    }
  }
}

// ---------------------------------------------------------------- finalize BN params
__global__ void k_finalize(const float* __restrict__ sum, const float* __restrict__ ssq,
                           const float* __restrict__ g, const float* __restrict__ bt,
                           float* __restrict__ scale, float* __restrict__ shift,
                           int nch, float inv_cnt) {
  int o = threadIdx.x + blockIdx.x * blockDim.x;
  if (o < nch) {
    float mean = sum[o] * inv_cnt;
    float var = ssq[o] * inv_cnt - mean * mean;
    float sc = g[o] * rsqrtf(var + EPSV);
    scale[o] = sc;
    shift[o] = bt[o] - mean * sc;
  }
}

// ---------------------------------------------------------------- pass C: stage2+stage3 MFMA
__global__ __launch_bounds__(256) void k_stage3(const float* __restrict__ h1,
                                                const float* __restrict__ hc,
                                                const float* __restrict__ sc1g,
                                                const float* __restrict__ sh1g,
                                                const ushort* __restrict__ W2b,
                                                const float* __restrict__ sc2g,
                                                const float* __restrict__ sh2g,
                                                const ushort* __restrict__ W3b,
                                                float* __restrict__ sum3,
                                                float* __restrict__ ssq3,
                                                float* __restrict__ Xmax,
                                                float* __restrict__ Xmin) {
  __shared__ __align__(16) ushort S1[M_ * C_];    // 16 KB
  __shared__ __align__(16) ushort S2[M_ * C2_];   // 32 KB
  __shared__ float h1row[C_], sc1[C_], sh1[C_];
  int row = blockIdx.x;
  build_S1(S1, h1, hc, sc1g, sh1g, row, h1row, sc1, sh1);
  int t = threadIdx.x, w = t >> 6, lane = t & 63, lr = lane & 15, lg = lane >> 4;

  // ---- stage 2: X2 = S1 . W2^T ; S2 = lrelu(bn2(X2)) (bf16, swizzled)
  {
    s16x8 b2[4][4];
    const ushort* w2base = W2b + (w * 64 + lr) * C_ + lg * 8;
#pragma unroll
    for (int ot = 0; ot < 4; ++ot)
#pragma unroll
      for (int ks = 0; ks < 4; ++ks)
        b2[ot][ks] = *(const s16x8*)(w2base + ot * 16 * C_ + ks * 32);
    float sc2v[4], sh2v[4];
#pragma unroll
    for (int ot = 0; ot < 4; ++ot) {
      int o = w * 64 + ot * 16 + lr;
      sc2v[ot] = sc2g[o]; sh2v[ot] = sh2g[o];
    }
#pragma unroll
    for (int mt = 0; mt < 4; ++mt) {
      int rowm = mt * 16 + lr, rx = rowm & 7;
      const ushort* s1r = S1 + rowm * C_;
      s16x8 a[4];
#pragma unroll
      for (int ks = 0; ks < 4; ++ks)
        a[ks] = *(const s16x8*)(s1r + (((ks * 4 + lg) ^ rx) << 3));
#pragma unroll
      for (int ot = 0; ot < 4; ++ot) {
        f32x4 acc = {0.f, 0.f, 0.f, 0.f};
#pragma unroll
        for (int ks = 0; ks < 4; ++ks)
          acc = __builtin_amdgcn_mfma_f32_16x16x32_bf16(a[ks], b2[ot][ks], acc, 0, 0, 0);
        int o = w * 64 + ot * 16 + lr;
        int oslot = o >> 3, olow = o & 7;
#pragma unroll
        for (int r = 0; r < 4; ++r) {
          int m = mt * 16 + lg * 4 + r;
          float x = fmaf(sc2v[ot], acc[r], sh2v[ot]);
          x = x > 0.f ? x : SLOPE * x;
          S2[m * C2_ + ((oslot ^ (m & 7)) << 3) + olow] = f2b(x);
        }
      }
    }
  }
  __syncthreads();

  // ---- stage 3: X3 = S2 . W3^T ; stats + per-(row,o) max/min over m
  float mx[4] = {-3.4e38f, -3.4e38f, -3.4e38f, -3.4e38f};
  float mn[4] = { 3.4e38f,  3.4e38f,  3.4e38f,  3.4e38f};
  float sm[4] = {0.f, 0.f, 0.f, 0.f}, sq[4] = {0.f, 0.f, 0.f, 0.f};
#pragma unroll
  for (int half = 0; half < 2; ++half) {
    s16x8 b3[2][8];
#pragma unroll
    for (int oi = 0; oi < 2; ++oi) {
      int o = w * 64 + (half * 2 + oi) * 16 + lr;
      const ushort* w3base = W3b + o * C2_ + lg * 8;
#pragma unroll
      for (int ks = 0; ks < 8; ++ks)
        b3[oi][ks] = *(const s16x8*)(w3base + ks * 32);
    }
#pragma unroll
    for (int mt = 0; mt < 4; ++mt) {
      int rowm = mt * 16 + lr, rx = rowm & 7;
      const ushort* s2r = S2 + rowm * C2_;
      s16x8 a[8];
#pragma unroll
      for (int ks = 0; ks < 8; ++ks)
        a[ks] = *(const s16x8*)(s2r + (((ks * 4 + lg) ^ rx) << 3));
#pragma unroll
      for (int oi = 0; oi < 2; ++oi) {
        f32x4 acc = {0.f, 0.f, 0.f, 0.f};
#pragma unroll
        for (int ks = 0; ks < 8; ++ks)
          acc = __builtin_amdgcn_mfma_f32_16x16x32_bf16(a[ks], b3[oi][ks], acc, 0, 0, 0);
        int ot = half * 2 + oi;
#pragma unroll
        for (int r = 0; r < 4; ++r) {
          float v = acc[r];
          mx[ot] = fmaxf(mx[ot], v);
          mn[ot] = fminf(mn[ot], v);
          sm[ot] += v;
          sq[ot] = fmaf(v, v, sq[ot]);
        }
      }
    }
  }
#pragma unroll
  for (int ot = 0; ot < 4; ++ot) {
    mx[ot] = fmaxf(mx[ot], __shfl_xor(mx[ot], 16)); mx[ot] = fmaxf(mx[ot], __shfl_xor(mx[ot], 32));
    mn[ot] = fminf(mn[ot], __shfl_xor(mn[ot], 16)); mn[ot] = fminf(mn[ot], __shfl_xor(mn[ot], 32));
    sm[ot] += __shfl_xor(sm[ot], 16); sm[ot] += __shfl_xor(sm[ot], 32);
    sq[ot] += __shfl_xor(sq[ot], 16); sq[ot] += __shfl_xor(sq[ot], 32);
  }
  if (lg == 0) {
#pragma unroll
    for (int ot = 0; ot < 4; ++ot) {
      int o = w * 64 + ot * 16 + lr;
      atomicAdd(&sum3[o], sm[ot]);
      atomicAdd(&ssq3[o], sq[ot]);
      Xmax[row * C2_ + o] = mx[ot];
      Xmin[row * C2_ + o] = mn[ot];
    }
  }
}

// ---------------------------------------------------------------- pool + fc1 (+stats4)
__global__ __launch_bounds__(128) void k_fc1(const float* __restrict__ Xmax,
                                             const float* __restrict__ Xmin,
                                             const float* __restrict__ sc3,
                                             const float* __restrict__ sh3,
                                             const float* __restrict__ w1,
                                             const float* __restrict__ b1v,
                                             float* __restrict__ X4,
                                             float* __restrict__ sum4,
                                             float* __restrict__ ssq4) {
  __shared__ float pooled[C2_];
  int row = blockIdx.x, t = threadIdx.x;
  for (int o = t; o < C2_; o += 128) {
    float sc = sc3[o];
    float v = sc >= 0.f ? Xmax[row * C2_ + o] : Xmin[row * C2_ + o];
    float x = fmaf(sc, v, sh3[o]);
    pooled[o] = x > 0.f ? x : SLOPE * x;
  }
  __syncthreads();
  const float* w = w1 + t * C2_;
  float acc = b1v[t];
#pragma unroll
  for (int c = 0; c < C2_; c += 4) {
    float4 wv = *(const float4*)(w + c);
    float4 pv = *(const float4*)(&pooled[c]);
    acc = fmaf(wv.x, pv.x, fmaf(wv.y, pv.y, fmaf(wv.z, pv.z, fmaf(wv.w, pv.w, acc))));
  }
  X4[row * H_ + t] = acc;
  atomicAdd(&sum4[t], acc);
  atomicAdd(&ssq4[t], acc * acc);
}

// ---------------------------------------------------------------- bn4+relu + fc2 (+stats5)
__global__ __launch_bounds__(64) void k_fc2(const float* __restrict__ X4,
                                            const float* __restrict__ sc4,
                                            const float* __restrict__ sh4,
                                            const float* __restrict__ w2,
                                            const float* __restrict__ b2v,
                                            float* __restrict__ X5,
                                            float* __restrict__ sum5,
                                            float* __restrict__ ssq5) {
  __shared__ float y[H_];
  int row = blockIdx.x, t = threadIdx.x;
  for (int j = t; j < H_; j += 64) {
    float x = fmaf(sc4[j], X4[row * H_ + j], sh4[j]);
    y[j] = x > 0.f ? x : 0.f;
  }
  __syncthreads();
  const float* w = w2 + t * H_;
  float acc = b2v[t];
#pragma unroll
  for (int c = 0; c < H_; c += 4) {
    float4 wv = *(const float4*)(w + c);
    float4 yv = *(const float4*)(&y[c]);
    acc = fmaf(wv.x, yv.x, fmaf(wv.y, yv.y, fmaf(wv.z, yv.z, fmaf(wv.w, yv.w, acc))));
  }
  X5[row * O_ + t] = acc;
  atomicAdd(&sum5[t], acc);
  atomicAdd(&ssq5[t], acc * acc);
}

// ---------------------------------------------------------------- bn5 + relu -> out
__global__ __launch_bounds__(256) void k_out(const float* __restrict__ X5,
                                             const float* __restrict__ sc5,
                                             const float* __restrict__ sh5,
                                             float* __restrict__ out) {
  int i = blockIdx.x * 256 + threadIdx.x;
  float x = fmaf(sc5[i & (O_ - 1)], X5[i], sh5[i & (O_ - 1)]);
  out[i] = x > 0.f ? x : 0.f;
}

// ---------------------------------------------------------------- launch
extern "C" void kernel_launch(void* const* d_in, const int* in_sizes, int n_in,
                              void* d_out, int out_size, void* d_ws, size_t ws_size,
                              hipStream_t stream) {
  const float* pf   = (const float*)d_in[0];
  const float* cf   = (const float*)d_in[1];
  const float* W1   = (const float*)d_in[2];
  const float* g1   = (const float*)d_in[3];
  const float* b1   = (const float*)d_in[4];
  const float* W2   = (const float*)d_in[5];
  const float* g2   = (const float*)d_in[6];
  const float* b2   = (const float*)d_in[7];
  const float* W3   = (const float*)d_in[8];
  const float* g3   = (const float*)d_in[9];
  const float* b3   = (const float*)d_in[10];
  const float* fc1w = (const float*)d_in[11];
  const float* fc1b = (const float*)d_in[12];
  const float* g4   = (const float*)d_in[13];
  const float* b4   = (const float*)d_in[14];
  const float* fc2w = (const float*)d_in[15];
  const float* fc2b = (const float*)d_in[16];
  const float* g5   = (const float*)d_in[17];
  const float* b5   = (const float*)d_in[18];
  float* ws  = (float*)d_ws;
  float* out = (float*)d_out;
  ushort* w2b = (ushort*)(ws + WS_W2BF);
  ushort* w3b = (ushort*)(ws + WS_W3BF);

  hipMemsetAsync(ws + WS_ZERO_BEG, 0, WS_ZERO_CNT * sizeof(float), stream);

  k_cvtW<<<(C2_ * C2_) / 256, 256, 0, stream>>>(W2, W3, w2b, w3b);
  k_proj<<<B_ * N_, 128, 0, stream>>>(pf, W1, ws + WS_H1, 0);
  k_proj<<<B_ * M_, 128, 0, stream>>>(cf, W1, ws + WS_HC, C_);
  k_stats1<<<C_, 256, 0, stream>>>(ws + WS_H1, ws + WS_HC, g1, b1, ws + WS_SC1, ws + WS_SH1);
  k_stats2<<<B_ * N_, 256, 0, stream>>>(ws + WS_H1, ws + WS_HC, ws + WS_SC1, ws + WS_SH1,
                                        w2b, ws + WS_SUM2, ws + WS_SSQ2);
  k_finalize<<<1, C2_, 0, stream>>>(ws + WS_SUM2, ws + WS_SSQ2, g2, b2,
                                    ws + WS_SC2, ws + WS_SH2, C2_, 1.f / (B_ * N_ * M_));
  k_stage3<<<B_ * N_, 256, 0, stream>>>(ws + WS_H1, ws + WS_HC, ws + WS_SC1, ws + WS_SH1,
                                        w2b, ws + WS_SC2, ws + WS_SH2, w3b,
                                        ws + WS_SUM3, ws + WS_SSQ3,
                                        ws + WS_XMAX, ws + WS_XMIN);
  k_finalize<<<1, C2_, 0, stream>>>(ws + WS_SUM3, ws + WS_SSQ3, g3, b3,
                                    ws + WS_SC3, ws + WS_SH3, C2_, 1.f / (B_ * N_ * M_));
  k_fc1<<<B_ * N_, 128, 0, stream>>>(ws + WS_XMAX, ws + WS_XMIN, ws + WS_SC3, ws + WS_SH3,
                                     fc1w, fc1b, ws + WS_X4, ws + WS_SUM4, ws + WS_SSQ4);
  k_finalize<<<1, H_, 0, stream>>>(ws + WS_SUM4, ws + WS_SSQ4, g4, b4,
                                   ws + WS_SC4, ws + WS_SH4, H_, 1.f / (B_ * N_));
  k_fc2<<<B_ * N_, 64, 0, stream>>>(ws + WS_X4, ws + WS_SC4, ws + WS_SH4,
                                    fc2w, fc2b, ws + WS_X5, ws + WS_SUM5, ws + WS_SSQ5);
  k_finalize<<<1, O_, 0, stream>>>(ws + WS_SUM5, ws + WS_SSQ5, g5, b5,
                                   ws + WS_SC5, ws + WS_SH5, O_, 1.f / (B_ * N_));
  k_out<<<(B_ * N_ * O_) / 256, 256, 0, stream>>>(ws + WS_X5, ws + WS_SC5, ws + WS_SH5, out);
}